// Round 17
// baseline (500.589 us; speedup 1.0000x reference)
//
#include <hip/hip_runtime.h>
#include <hip/hip_bf16.h>
#include <math.h>

// ---------------------------------------------------------------------------
// GPT block fused pipeline, bf16 MFMA. B=4,S=2048,D=1024,H=16,HD=64.
// ws layout (bytes):
//   W1t  @ 0         : 3072x1024 bf16 (W_attn^T)   6291456
//   W2t  @ 6291456   : 1024x1024 bf16 (W_cproj^T)  2097152
//   W3t  @ 8388608   : 4096x1024 bf16 (W_fc^T)     8388608
//   W4t  @ 16777216  : 1024x4096 bf16 (W_mproj^T)  8388608
//   h    @ 25165824  : 8192x1024 bf16 (ln out; attn O0buf; mproj p0)
//   aout @ 41943040  : 8192x1024 bf16 (attn out; mproj partial1)
//   big  @ 58720256  : 8192x3072 bf16 qkv; then cproj partials; then fc-act
//   total 125829120 bytes.  x2 (residual after attn) lives in d_out (fp32).
//   d_out is DEAD until reduce_ln -> used as attn scratch (O2/O3/ml2-4).
// R7: GEMMs on 256^2 8-phase (T2+T3/T4+T5). R8: attn tr_read+cvt_pk.
// R14: conflict-free V staging + T14. R16: T13+T5+trees. R18: K/V dbuf,
// 1 barrier/tile. R21: prep fusion. R22: epilogue line-order (write-amp fix,
// mproj 127->~90). 603.5 -> 491.8 us.
// R23: attn TAIL REBALANCE -- occupancy ~20% == only the 512 16-tile blocks
// running most of the time. Split so max chunk = 12 tiles:
//   qt8-15: A=[0,12) ->O0buf(m0/l0); B=[12,min(24,kthi)) ->aout(m1/l1);
//           C=[24,kthi) qt>=12 ->O2buf(m2/l2).
//   qt4-7:  [0,qt+1) ->O3buf(m3/l3); [qt+1,2qt+2) ->aout(m4/l4).
//   qt0-3:  direct. Grid (64,32); combine 768 blocks, 2/3-way by qt.
// ---------------------------------------------------------------------------

typedef __attribute__((ext_vector_type(8))) short short8;
typedef __attribute__((ext_vector_type(4))) float floatx4;
typedef __attribute__((ext_vector_type(2))) unsigned int uint2v;

#define MFMA16(a, b, c) __builtin_amdgcn_mfma_f32_16x16x32_bf16((a), (b), (c), 0, 0, 0)

__device__ __forceinline__ short f2bf(float f) {
    union { float f; unsigned u; } a; a.f = f;
    unsigned r = a.u + 0x7fffu + ((a.u >> 16) & 1u);   // round-to-nearest-even
    return (short)(r >> 16);
}

__device__ __forceinline__ float bf2f(unsigned short u) {
    union { unsigned u; float f; } a; a.u = ((unsigned)u) << 16;
    return a.f;
}

__device__ __forceinline__ float fast_rcp(float x) {
#if defined(__HIP_DEVICE_COMPILE__)
    return __builtin_amdgcn_rcpf(x);
#else
    return 1.0f / x;
#endif
}

// gelu(x) = 0.5x(1+tanh(u)) = x - x/(e^{2u}+1),  u = 0.79788456(x+0.044715x^3)
__device__ __forceinline__ float gelu_f(float x) {
    const float u = x + 0.044715f * x * x * x;
    const float t = exp2f(2.302118131f * u);   // 2*0.79788456*log2(e)*u
    return x - x * fast_rcp(t + 1.0f);
}

__device__ __forceinline__ void gload_lds16(const short* g, short* l) {
    __builtin_amdgcn_global_load_lds((const __attribute__((address_space(1))) void*)g,
                                     (__attribute__((address_space(3))) void*)l, 16, 0, 0);
}

// ---------------- fused prologue: 4x transpose-cast + LayerNorm --------------
__device__ __forceinline__ void tcast_body(const float* __restrict__ W,
                                           short* __restrict__ Wt,
                                           int K, int N, int bxi, int byi,
                                           float* __restrict__ tile) {
    const int t = threadIdx.x;
    const int tx = t & 31;
    const int ty = t >> 5;
    const int bx = bxi * 32;   // n
    const int by = byi * 32;   // k
#pragma unroll
    for (int i = 0; i < 32; i += 8)
        tile[(ty + i) * 33 + tx] = W[(size_t)(by + ty + i) * N + bx + tx];
    __syncthreads();
#pragma unroll
    for (int i = 0; i < 32; i += 8)
        Wt[(size_t)(bx + ty + i) * K + by + tx] = f2bf(tile[tx * 33 + ty + i]);
}

__global__ __launch_bounds__(256) void prep_kernel(
    const float* __restrict__ x, const float* __restrict__ ln_w,
    const float* __restrict__ ln_b, short* __restrict__ hout,
    const float* __restrict__ W_attn, short* __restrict__ W1t,
    const float* __restrict__ W_cproj, short* __restrict__ W2t,
    const float* __restrict__ W_fc, short* __restrict__ W3t,
    const float* __restrict__ W_mproj, short* __restrict__ W4t) {
    __shared__ float smem_f[32 * 33];
    int bid = blockIdx.x;
    if (bid < 8192) {
        // ---- LayerNorm row ----
        const int row = bid;
        const int t = threadIdx.x;
        const float4 v = ((const float4*)(x + (size_t)row * 1024))[t];
        float s = v.x + v.y + v.z + v.w;
        float s2 = v.x * v.x + v.y * v.y + v.z * v.z + v.w * v.w;
#pragma unroll
        for (int d = 32; d >= 1; d >>= 1) {
            s += __shfl_xor(s, d, 64);
            s2 += __shfl_xor(s2, d, 64);
        }
        float* red = smem_f;
        const int wid = t >> 6, lane = t & 63;
        if (lane == 0) { red[wid * 2] = s; red[wid * 2 + 1] = s2; }
        __syncthreads();
        s = red[0] + red[2] + red[4] + red[6];
        s2 = red[1] + red[3] + red[5] + red[7];
        const float mean = s * (1.f / 1024.f);
        const float var = s2 * (1.f / 1024.f) - mean * mean;
        const float rstd = rsqrtf(var + 1e-5f);
        const float4 wv = ((const float4*)ln_w)[t];
        const float4 bv = ((const float4*)ln_b)[t];
        union { ushort4 u; short sa[4]; } ov;
        ov.sa[0] = f2bf(wv.x * ((v.x - mean) * rstd) + bv.x);
        ov.sa[1] = f2bf(wv.y * ((v.y - mean) * rstd) + bv.y);
        ov.sa[2] = f2bf(wv.z * ((v.z - mean) * rstd) + bv.z);
        ov.sa[3] = f2bf(wv.w * ((v.w - mean) * rstd) + bv.w);
        ((ushort4*)(hout + (size_t)row * 1024))[t] = ov.u;
        return;
    }
    bid -= 8192;
    if (bid < 3072) {            // W_attn: K=1024 N=3072, gx=96
        tcast_body(W_attn, W1t, 1024, 3072, bid % 96, bid / 96, smem_f);
        return;
    }
    bid -= 3072;
    if (bid < 1024) {            // W_cproj: K=1024 N=1024, gx=32
        tcast_body(W_cproj, W2t, 1024, 1024, bid % 32, bid / 32, smem_f);
        return;
    }
    bid -= 1024;
    if (bid < 4096) {            // W_fc: K=1024 N=4096, gx=128
        tcast_body(W_fc, W3t, 1024, 4096, bid % 128, bid / 128, smem_f);
        return;
    }
    bid -= 4096;                 // W_mproj: K=4096 N=1024, gx=32
    tcast_body(W_mproj, W4t, 4096, 1024, bid % 32, bid / 32, smem_f);
}

// ------- reduce: out = bf16(p0) + bf16(p1) + bias + res (all [8192][1024]) ---
__global__ __launch_bounds__(256) void reduce_kernel(
    const unsigned short* __restrict__ p0, const unsigned short* __restrict__ p1,
    const float* __restrict__ bias, const float* __restrict__ res,
    float* __restrict__ out) {
    const int row = blockIdx.x;
    const int t = threadIdx.x;
    const size_t off = (size_t)row * 1024;
    const ushort4 a = ((const ushort4*)(p0 + off))[t];
    const ushort4 c = ((const ushort4*)(p1 + off))[t];
    const float4 r = ((const float4*)(res + off))[t];
    const float4 bv = ((const float4*)bias)[t];
    float4 o;
    o.x = bf2f(a.x) + bf2f(c.x) + bv.x + r.x;
    o.y = bf2f(a.y) + bf2f(c.y) + bv.y + r.y;
    o.z = bf2f(a.z) + bf2f(c.z) + bv.z + r.z;
    o.w = bf2f(a.w) + bf2f(c.w) + bv.w + r.w;
    ((float4*)(out + off))[t] = o;
}

// ------- fused: x2 = p0+p1+bias+res;  h = LN(x2)*w+b (saves a full pass) -----
__global__ __launch_bounds__(256) void reduce_ln_kernel(
    const unsigned short* __restrict__ p0, const unsigned short* __restrict__ p1,
    const float* __restrict__ bias, const float* __restrict__ res,
    float* __restrict__ x2out,
    const float* __restrict__ w, const float* __restrict__ b,
    short* __restrict__ hout) {
    const int row = blockIdx.x;
    const int t = threadIdx.x;
    const size_t off = (size_t)row * 1024;
    const ushort4 a = ((const ushort4*)(p0 + off))[t];
    const ushort4 c = ((const ushort4*)(p1 + off))[t];
    const float4 r = ((const float4*)(res + off))[t];
    const float4 bv = ((const float4*)bias)[t];
    float4 v;
    v.x = bf2f(a.x) + bf2f(c.x) + bv.x + r.x;
    v.y = bf2f(a.y) + bf2f(c.y) + bv.y + r.y;
    v.z = bf2f(a.z) + bf2f(c.z) + bv.z + r.z;
    v.w = bf2f(a.w) + bf2f(c.w) + bv.w + r.w;
    ((float4*)(x2out + off))[t] = v;
    float s = v.x + v.y + v.z + v.w;
    float s2 = v.x * v.x + v.y * v.y + v.z * v.z + v.w * v.w;
#pragma unroll
    for (int d = 32; d >= 1; d >>= 1) {
        s += __shfl_xor(s, d, 64);
        s2 += __shfl_xor(s2, d, 64);
    }
    __shared__ float red[8];
    const int wid = t >> 6, lane = t & 63;
    if (lane == 0) { red[wid * 2] = s; red[wid * 2 + 1] = s2; }
    __syncthreads();
    s = red[0] + red[2] + red[4] + red[6];
    s2 = red[1] + red[3] + red[5] + red[7];
    const float mean = s * (1.f / 1024.f);
    const float var = s2 * (1.f / 1024.f) - mean * mean;
    const float rstd = rsqrtf(var + 1e-5f);
    const float4 wv = ((const float4*)w)[t];
    const float4 lb = ((const float4*)b)[t];
    union { ushort4 u; short sa[4]; } ov;
    ov.sa[0] = f2bf(wv.x * ((v.x - mean) * rstd) + lb.x);
    ov.sa[1] = f2bf(wv.y * ((v.y - mean) * rstd) + lb.y);
    ov.sa[2] = f2bf(wv.z * ((v.z - mean) * rstd) + lb.z);
    ov.sa[3] = f2bf(wv.w * ((v.w - mean) * rstd) + lb.w);
    ((ushort4*)(hout + (size_t)row * 1024))[t] = ov.u;
}

// ---------------- GEMM 256^2 8-phase (qkv / cproj / fc / mproj) --------------
#define GBAR()  asm volatile("s_barrier" ::: "memory")
#define LGKM0() asm volatile("s_waitcnt lgkmcnt(0)" ::: "memory")
#define STAGE_A(b_, kt_, p_)                                                   \
    do {                                                                       \
        gload_lds16(gA + (size_t)((p_) * 128) * lda + (kt_) * 64,              \
                    lA + (b_) * 16384 + (p_) * 8192);                          \
        gload_lds16(gA + (size_t)((p_) * 128 + 64) * lda + (kt_) * 64,         \
                    lA + (b_) * 16384 + (p_) * 8192 + 4096);                   \
    } while (0)
#define STAGE_B(b_, kt_, p_)                                                   \
    do {                                                                       \
        gload_lds16(gB + (size_t)((p_) * 128) * ldb + (kt_) * 64,              \
                    lB + (b_) * 16384 + (p_) * 8192);                          \
        gload_lds16(gB + (size_t)((p_) * 128 + 64) * ldb + (kt_) * 64,         \
                    lB + (b_) * 16384 + (p_) * 8192 + 4096);                   \
    } while (0)

template <int EPI>
__global__ __launch_bounds__(512, 2) void gemm256_kernel(
    const short* __restrict__ A, const short* __restrict__ Bt,
    const float* __restrict__ bias,
    void* __restrict__ Cout, int M, int N, int Klen, int lda, int ldb) {
    extern __shared__ __align__(16) short lds[];
    short* As = lds;             // [2][256][64]
    short* Bs = lds + 32768;     // [2][256][64]

    const int tid = threadIdx.x;
    const int wid = tid >> 6;
    const int lane = tid & 63;
    const int quad = lane >> 4;
    const int l16 = lane & 15;
    const int l7 = l16 & 7;
    const int warp_m = wid >> 2;       // 0..1
    const int warp_n = wid & 3;        // 0..3

    const unsigned gx = gridDim.x;
    const unsigned bid2 = blockIdx.x + gx * blockIdx.y;   // gridDim.y == 32
    const unsigned xcd = bid2 & 7;
    const unsigned loc = bid2 >> 3;
    const unsigned nb = loc % gx;
    const unsigned mhi = loc / gx;     // 0..3
    const int m0 = (int)(mhi * 8 + xcd) * 256;
    const int n0 = (int)nb * 256;
    const int kbase = blockIdx.z * Klen;
    const int NT = Klen >> 6;

    // staging: thread covers dest byte o = i*8192 + tid*16 of a 256x128B tile.
    const int rsub = tid >> 3;
    const int scol = ((tid & 7) ^ (rsub & 7)) << 3;      // shorts
    const short* gA = A + (size_t)(m0 + rsub) * lda + kbase + scol;
    const short* gB = Bt + (size_t)(n0 + rsub) * ldb + kbase + scol;
    short* lA = As + wid * 512;        // + b*16384 + i*4096  (wave-uniform)
    short* lB = Bs + wid * 512;

    // ds_read swizzle: logical col bytes = ks*64 + quad*16; bits[6:4] ^= l7.
    const int sk0 = ((0 | quad) ^ l7) << 3;              // shorts, ks=0
    const int sk1 = ((4 | quad) ^ l7) << 3;              // shorts, ks=1

    floatx4 acc[8][4] = {};
    short8 afrag[4][2], bA[2][2], bB[2][2];

    // ---- prologue: tile0 fully + H1(1); wait leaving H1(1) in flight -------
    STAGE_A(0, 0, 0); STAGE_A(0, 0, 1);
    STAGE_B(0, 0, 0); STAGE_B(0, 0, 1);
    if (NT > 1) {
        STAGE_A(1, 1, 0);
        asm volatile("s_waitcnt vmcnt(2)" ::: "memory");
    } else {
        asm volatile("s_waitcnt vmcnt(0)" ::: "memory");
    }
    GBAR();

    for (int t = 0; t < NT; ++t) {
        const int b = t & 1;
        const int bn = b ^ 1;
        const short* Ab = As + b * 16384 + (warp_m * 128 + l16) * 64;
        const short* Bb = Bs + b * 16384 + (warp_n * 64 + l16) * 64;
        // ---------------- P1: read A(mi0-3), B(ni0-1); stage H2(t+1) --------
#pragma unroll
        for (int mi = 0; mi < 4; mi++) {
            afrag[mi][0] = *(const short8*)(Ab + mi * 1024 + sk0);
            afrag[mi][1] = *(const short8*)(Ab + mi * 1024 + sk1);
        }
#pragma unroll
        for (int ni = 0; ni < 2; ni++) {
            bA[ni][0] = *(const short8*)(Bb + ni * 1024 + sk0);
            bA[ni][1] = *(const short8*)(Bb + ni * 1024 + sk1);
        }
        if (t + 1 < NT) STAGE_A(bn, t + 1, 1);
        GBAR(); LGKM0();
        __builtin_amdgcn_s_setprio(1);
#pragma unroll
        for (int mi = 0; mi < 4; mi++)
#pragma unroll
            for (int ni = 0; ni < 2; ni++) {
                acc[mi][ni] = MFMA16(afrag[mi][0], bA[ni][0], acc[mi][ni]);
                acc[mi][ni] = MFMA16(afrag[mi][1], bA[ni][1], acc[mi][ni]);
            }
        __builtin_amdgcn_s_setprio(0);
        GBAR();
        // ---------------- P2: read B(ni2-3); stage H3(t+1) ------------------
#pragma unroll
        for (int ni = 0; ni < 2; ni++) {
            bB[ni][0] = *(const short8*)(Bb + (2 + ni) * 1024 + sk0);
            bB[ni][1] = *(const short8*)(Bb + (2 + ni) * 1024 + sk1);
        }
        if (t + 1 < NT) STAGE_B(bn, t + 1, 0);
        GBAR(); LGKM0();
        __builtin_amdgcn_s_setprio(1);
#pragma unroll
        for (int mi = 0; mi < 4; mi++)
#pragma unroll
            for (int ni = 0; ni < 2; ni++) {
                acc[mi][2 + ni] = MFMA16(afrag[mi][0], bB[ni][0], acc[mi][2 + ni]);
                acc[mi][2 + ni] = MFMA16(afrag[mi][1], bB[ni][1], acc[mi][2 + ni]);
            }
        __builtin_amdgcn_s_setprio(0);
        GBAR();
        // ---------------- P3: read A(mi4-7); stage H4(t+1) ------------------
#pragma unroll
        for (int mi = 0; mi < 4; mi++) {
            afrag[mi][0] = *(const short8*)(Ab + (4 + mi) * 1024 + sk0);
            afrag[mi][1] = *(const short8*)(Ab + (4 + mi) * 1024 + sk1);
        }
        if (t + 1 < NT) STAGE_B(bn, t + 1, 1);
        GBAR(); LGKM0();
        __builtin_amdgcn_s_setprio(1);
#pragma unroll
        for (int mi = 0; mi < 4; mi++)
#pragma unroll
            for (int ni = 0; ni < 2; ni++) {
                acc[4 + mi][2 + ni] = MFMA16(afrag[mi][0], bB[ni][0], acc[4 + mi][2 + ni]);
                acc[4 + mi][2 + ni] = MFMA16(afrag[mi][1], bB[ni][1], acc[4 + mi][2 + ni]);
            }
        __builtin_amdgcn_s_setprio(0);
        GBAR();
        // ---------------- P4: stage H1(t+2); counted vmcnt ------------------
        if (t + 2 < NT) STAGE_A(b, t + 2, 0);
        GBAR();
        __builtin_amdgcn_s_setprio(1);
#pragma unroll
        for (int mi = 0; mi < 4; mi++)
#pragma unroll
            for (int ni = 0; ni < 2; ni++) {
                acc[4 + mi][ni] = MFMA16(afrag[mi][0], bA[ni][0], acc[4 + mi][ni]);
                acc[4 + mi][ni] = MFMA16(afrag[mi][1], bA[ni][1], acc[4 + mi][ni]);
            }
        __builtin_amdgcn_s_setprio(0);
        if (t + 2 < NT) asm volatile("s_waitcnt vmcnt(2)" ::: "memory");
        else            asm volatile("s_waitcnt vmcnt(0)" ::: "memory");
        GBAR();
    }

    // ---- epilogue (R22: line-completing store order, ni innermost) ---------
    float bv4[4] = {0.f, 0.f, 0.f, 0.f};
    if constexpr (EPI != 3) {
#pragma unroll
        for (int ni = 0; ni < 4; ni++)
            bv4[ni] = bias[n0 + warp_n * 64 + ni * 16 + l16];
    }
#pragma unroll
    for (int mi = 0; mi < 8; mi++) {
#pragma unroll
        for (int r = 0; r < 4; r++) {
            const int row = m0 + warp_m * 128 + mi * 16 + quad * 4 + r;
            const size_t rowoff = (size_t)row * N + n0 + warp_n * 64 + l16;
#pragma unroll
            for (int ni = 0; ni < 4; ni++) {
                const size_t idx = rowoff + ni * 16;
                float v = acc[mi][ni][r] + bv4[ni];
                if constexpr (EPI == 0) {
                    ((short*)Cout)[idx] = f2bf(v);
                } else if constexpr (EPI == 1) {
                    ((short*)Cout)[idx] = f2bf(gelu_f(v));
                } else {
                    ((short*)Cout)[(size_t)blockIdx.z * M * N + idx] = f2bf(v);
                }
            }
        }
    }
}
#undef STAGE_A
#undef STAGE_B
#undef GBAR
#undef LGKM0

// ---------------- causal flash attention (S^T formulation, K-split) ----------
// R23 mapping, blockIdx.y in [0,32):
//   y 0..7  : qt=8+y,      kt [0,12)               mode1 -> O0buf, m0/l0
//   y 8..15 : qt=8+(y-8),  kt [12,min(24,kthi))    mode2 -> aout,  m1/l1
//   y 16..19: qt=12+(y-16),kt [24,kthi)            mode3 -> O2buf, m2/l2
//   y 20..23: qt=y-20,     kt [0,kthi) (<=8)       mode0 direct (normalized)
//   y 24..27: qt=4+(y-24), kt [0,qt+1)             mode4 -> O3buf, m3/l3
//   y 28..31: qt=4+(y-28), kt [qt+1,2qt+2)         mode5 -> aout,  m4/l4
// Max chunk = 12 tiles (was 16): cuts the straggler tail that capped
// occupancy at ~20%. Partials UNNORMALIZED. Scratch (O2/O3/ml2-4) in d_out.
__global__ __launch_bounds__(256) void attn_kernel(
    const short* __restrict__ qkv, short* __restrict__ aout,
    short* __restrict__ O0buf, float* __restrict__ m0p, float* __restrict__ l0p,
    float* __restrict__ m1p, float* __restrict__ l1p, char* __restrict__ scratch) {
    __shared__ __align__(16) short smem[18432];  // 2 x (Ks[64][72] | Vt[4096])
    short* Ks = smem;                            // + (kt&1)*9216
    short* Vt = smem + 64 * 72;

    short* O2buf = (short*)scratch;                       // 256 slots x 16KB
    short* O3buf = (short*)(scratch + 4194304);           // 256 slots x 16KB
    float* m2p = (float*)(scratch + 8388608);
    float* l2p = (float*)(scratch + 8519680);
    float* m3p = (float*)(scratch + 8650752);
    float* l3p = (float*)(scratch + 8781824);
    float* m4p = (float*)(scratch + 8912896);
    float* l4p = (float*)(scratch + 9043968);

    const int tid = threadIdx.x;
    const int wid = tid >> 6;
    const int lane = tid & 63;
    const int quad = lane >> 4;
    const int l16 = lane & 15;

    const int y = blockIdx.y;
    int qt, ktlo, kthi, mode;
    if (y < 8)       { qt = 8 + y;        ktlo = 0;       kthi = 12;                      mode = 1; }
    else if (y < 16) { qt = 8 + (y - 8);  ktlo = 12;      kthi = min(24, (qt + 1) * 2);   mode = 2; }
    else if (y < 20) { qt = 12 + (y - 16);ktlo = 24;      kthi = (qt + 1) * 2;            mode = 3; }
    else if (y < 24) { qt = y - 20;       ktlo = 0;       kthi = (qt + 1) * 2;            mode = 0; }
    else if (y < 28) { qt = 4 + (y - 24); ktlo = 0;       kthi = qt + 1;                  mode = 4; }
    else             { qt = 4 + (y - 28); ktlo = qt + 1;  kthi = (qt + 1) * 2;            mode = 5; }
    const int q0 = qt * 128;
    const int bh = blockIdx.x;
    const int b = bh >> 4;
    const int h = bh & 15;

    const short* base = qkv + (size_t)b * 2048 * 3072 + h * 64;
    const int qrow_base = q0 + wid * 32;

    short8 qf[2][2];
#pragma unroll
    for (int qt_i = 0; qt_i < 2; qt_i++)
#pragma unroll
        for (int ks = 0; ks < 2; ks++)
            qf[qt_i][ks] = *(const short8*)(base +
                (size_t)(qrow_base + qt_i * 16 + l16) * 3072 + ks * 32 + quad * 8);

    // ---- staging addresses (R14) ----
    const int kr_ = tid >> 2;                 // K row 0..63
    const int kcg = (tid & 3) * 16;           // K col group (shorts)
    const short* ksrc = base + 1024 + kcg;    // + (kt0+kr_)*3072
    short* kdst = &Ks[kr_ * 72 + kcg];
    const int vrA = ((lane >> 3) << 2) | ((lane >> 1) & 3);   // V row (lane-local)
    const short* vsrc = base + 2048 + wid * 16 + (lane & 1) * 8;  // + (kt0+row)*3072
    short* vdst = Vt + wid * 1024 + lane * 8;  // bytes w*2048 + i*16; +512 shorts

    // lane-local byte address into Vt for ds_read_b64_tr_b16
    const unsigned vaddr0 =
        (unsigned)(size_t)(__attribute__((address_space(3))) void*)Vt +
        (unsigned)(quad * 128 + l16 * 8);

    union VF { short8 s; uint2v h2[2]; };
    union PK { short8 s; unsigned u[4]; };

    floatx4 o[4][2] = {};           // O^T: [dt][qt_i]
    float mrow[2] = {-1e30f, -1e30f};
    float lrow[2] = {0.f, 0.f};
    const float SCL = 0.125f * 1.44269504f;  // raw-score -> log2 units

    uint4 krg0, krg1, vrg0, vrg1;
#define LOADREG(kt0_)                                                          \
    do {                                                                       \
        const short* kp = ksrc + (size_t)((kt0_) + kr_) * 3072;                \
        krg0 = ((const uint4*)kp)[0];                                          \
        krg1 = ((const uint4*)kp)[1];                                          \
        vrg0 = *(const uint4*)(vsrc + (size_t)((kt0_) + vrA) * 3072);          \
        vrg1 = *(const uint4*)(vsrc + (size_t)((kt0_) + vrA + 32) * 3072);     \
    } while (0)

    LOADREG(ktlo * 64);
    for (int kt = ktlo; kt < kthi; kt++) {
        const int kt0 = kt * 64;
        const int bo = (kt & 1) * 9216;            // LDS buffer offset (shorts)
        // write staged regs to LDS buf[kt&1], then issue next tile's loads
        *(uint4*)(kdst + bo) = krg0;
        *(uint4*)(kdst + bo + 8) = krg1;
        *(uint4*)(vdst + bo) = vrg0;
        *(uint4*)(vdst + bo + 512) = vrg1;
        if (kt + 1 < kthi) LOADREG((kt + 1) * 64);
        __syncthreads();   // single barrier per tile (R18 dbuf argument)
        if (kt0 <= qrow_base + 31) {
            floatx4 st[4][2] = {};
            __builtin_amdgcn_s_setprio(1);
#pragma unroll
            for (int kti = 0; kti < 4; kti++) {
                const short8 kf0 = *(const short8*)&Ks[bo + (kti * 16 + l16) * 72 + quad * 8];
                const short8 kf1 = *(const short8*)&Ks[bo + (kti * 16 + l16) * 72 + 32 + quad * 8];
#pragma unroll
                for (int qt_i = 0; qt_i < 2; qt_i++) {
                    st[kti][qt_i] = MFMA16(kf0, qf[qt_i][0], st[kti][qt_i]);
                    st[kti][qt_i] = MFMA16(kf1, qf[qt_i][1], st[kti][qt_i]);
                }
            }
            __builtin_amdgcn_s_setprio(0);
            // issue all 16 V transpose-reads now; latency hides under softmax.
            const unsigned va = vaddr0 + (unsigned)(bo * 2);
            VF vf[2][4];   // [c][dt]; offset = dt*2048 + c*1024 + h*512 bytes
#define TRRD(dst, offs) \
    asm volatile("ds_read_b64_tr_b16 %0, %1 offset:" offs : "=v"(dst) : "v"(va))
            TRRD(vf[0][0].h2[0], "0");    TRRD(vf[0][0].h2[1], "512");
            TRRD(vf[0][1].h2[0], "2048"); TRRD(vf[0][1].h2[1], "2560");
            TRRD(vf[0][2].h2[0], "4096"); TRRD(vf[0][2].h2[1], "4608");
            TRRD(vf[0][3].h2[0], "6144"); TRRD(vf[0][3].h2[1], "6656");
            TRRD(vf[1][0].h2[0], "1024"); TRRD(vf[1][0].h2[1], "1536");
            TRRD(vf[1][1].h2[0], "3072"); TRRD(vf[1][1].h2[1], "3584");
            TRRD(vf[1][2].h2[0], "5120"); TRRD(vf[1][2].h2[1], "5632");
            TRRD(vf[1][3].h2[0], "7168"); TRRD(vf[1][3].h2[1], "7680");
#undef TRRD
            const bool needmask = (kt0 + 63) > qrow_base;
            PK pk[2][2];
#pragma unroll
            for (int qt_i = 0; qt_i < 2; qt_i++) {
                const int q = qrow_base + qt_i * 16 + l16;
                if (needmask) {
#pragma unroll
                    for (int kti = 0; kti < 4; kti++)
#pragma unroll
                        for (int r = 0; r < 4; r++)
                            if ((kt0 + kti * 16 + quad * 4 + r) > q) st[kti][qt_i][r] = -1e30f;
                }
                // tree max (depth 4)
                float mk[4];
#pragma unroll
                for (int kti = 0; kti < 4; kti++)
                    mk[kti] = fmaxf(fmaxf(st[kti][qt_i][0], st[kti][qt_i][1]),
                                    fmaxf(st[kti][qt_i][2], st[kti][qt_i][3]));
                float mx = fmaxf(fmaxf(mk[0], mk[1]), fmaxf(mk[2], mk[3]));
                mx = fmaxf(mx, __shfl_xor(mx, 16, 64));
                mx = fmaxf(mx, __shfl_xor(mx, 32, 64));
                // T13 defer-max
                if (!__all((mx - mrow[qt_i]) <= 8.0f)) {
                    const float mnew = fmaxf(mrow[qt_i], mx);
                    const float alpha = exp2f((mrow[qt_i] - mnew) * SCL);
                    mrow[qt_i] = mnew;
                    lrow[qt_i] *= alpha;
#pragma unroll
                    for (int dt = 0; dt < 4; dt++) o[dt][qt_i] *= alpha;
                }
                const float nm = -mrow[qt_i] * SCL;
#pragma unroll
                for (int kti = 0; kti < 4; kti++)
#pragma unroll
                    for (int r = 0; r < 4; r++)
                        st[kti][qt_i][r] = exp2f(fmaf(st[kti][qt_i][r], SCL, nm));
                // tree sum
                float sk_[4];
#pragma unroll
                for (int kti = 0; kti < 4; kti++)
                    sk_[kti] = (st[kti][qt_i][0] + st[kti][qt_i][1]) +
                               (st[kti][qt_i][2] + st[kti][qt_i][3]);
                float ps = (sk_[0] + sk_[1]) + (sk_[2] + sk_[3]);
                ps += __shfl_xor(ps, 16, 64);
                ps += __shfl_xor(ps, 32, 64);
                lrow[qt_i] += ps;
                // P -> bf16 via packed converts
#define CVTPK(dst, lo, hi) \
    asm("v_cvt_pk_bf16_f32 %0, %1, %2" : "=v"(dst) : "v"(lo), "v"(hi))
                CVTPK(pk[0][qt_i].u[0], st[0][qt_i][0], st[0][qt_i][1]);
                CVTPK(pk[0][qt_i].u[1], st[0][qt_i][2], st[0][qt_i][3]);
                CVTPK(pk[0][qt_i].u[2], st[1][qt_i][0], st[1][qt_i][1]);
                CVTPK(pk[0][qt_i].u[3], st[1][qt_i][2], st[1][qt_i][3]);
                CVTPK(pk[1][qt_i].u[0], st[2][qt_i][0], st[2][qt_i][1]);
                CVTPK(pk[1][qt_i].u[1], st[2][qt_i][2], st[2][qt_i][3]);
                CVTPK(pk[1][qt_i].u[2], st[3][qt_i][0], st[3][qt_i][1]);
                CVTPK(pk[1][qt_i].u[3], st[3][qt_i][2], st[3][qt_i][3]);
#undef CVTPK
            }
            asm volatile("s_waitcnt lgkmcnt(0)" ::: "memory");
            __builtin_amdgcn_sched_barrier(0);
            __builtin_amdgcn_s_setprio(1);
#pragma unroll
            for (int c = 0; c < 2; c++)
#pragma unroll
                for (int dt = 0; dt < 4; dt++) {
                    o[dt][0] = MFMA16(vf[c][dt].s, pk[c][0].s, o[dt][0]);
                    o[dt][1] = MFMA16(vf[c][dt].s, pk[c][1].s, o[dt][1]);
                }
            __builtin_amdgcn_s_setprio(0);
        }
        // no trailing barrier: next iteration writes the OTHER buffer.
    }
#undef LOADREG
    __syncthreads();   // all waves done with K/V buffers before Ow reuse
    // ---- epilogue target selection (R23) ----
    int slot = 0;
    short* Opart = nullptr;          // nullptr => aout
    float* mp = nullptr; float* lp = nullptr;
    switch (mode) {
        case 1: slot = (qt - 8) * 64 + bh;  Opart = O0buf; mp = m0p; lp = l0p; break;
        case 2: slot = (qt - 8) * 64 + bh;  mp = m1p; lp = l1p; break;
        case 3: slot = (qt - 12) * 64 + bh; Opart = O2buf; mp = m2p; lp = l2p; break;
        case 4: slot = (qt - 4) * 64 + bh;  Opart = O3buf; mp = m3p; lp = l3p; break;
        case 5: slot = (qt - 4) * 64 + bh;  mp = m4p; lp = l4p; break;
        default: break;
    }
    short* Ow = smem + wid * (32 * 72);
    const float rl0 = (mode == 0) ? fast_rcp(lrow[0]) : 1.0f;
    const float rl1 = (mode == 0) ? fast_rcp(lrow[1]) : 1.0f;
#pragma unroll
    for (int dt = 0; dt < 4; dt++)
#pragma unroll
        for (int r = 0; r < 4; r++) {
            Ow[(l16) * 72 + dt * 16 + quad * 4 + r] = f2bf(o[dt][0][r] * rl0);
            Ow[(16 + l16) * 72 + dt * 16 + quad * 4 + r] = f2bf(o[dt][1][r] * rl1);
        }
    if (mode != 0 && quad == 0) {   // per-q m/l
        const int qi0 = slot * 128 + (qrow_base - q0) + l16;
        mp[qi0] = mrow[0]; lp[qi0] = lrow[0];
        mp[qi0 + 16] = mrow[1]; lp[qi0 + 16] = lrow[1];
    }
    __asm__ volatile("s_waitcnt lgkmcnt(0)" ::: "memory");
    {
        const int ql = lane >> 1;
        const int h2 = lane & 1;
        short* orow;
        if (Opart)
            orow = Opart + (size_t)slot * 8192 + (size_t)(wid * 32 + ql) * 64 + h2 * 32;
        else
            orow = aout + (size_t)(b * 2048 + q0 + wid * 32 + ql) * 1024 + h * 64 + h2 * 32;
#pragma unroll
        for (int s = 0; s < 4; s++)
            *(uint4*)(orow + s * 8) = *(const uint4*)&Ow[ql * 72 + h2 * 32 + s * 8];
    }
}

// ------- attention combine (R23): 2-way or 3-way per qt ----------------------
// grid 768: s<512 -> qt 8..15 (O0buf + aout [+ O2buf if qt>=12]);
//           s>=512 -> qt 4..7 (O3buf + aout).
__global__ __launch_bounds__(256) void attn_combine_kernel(
    const short* __restrict__ O0buf, short* __restrict__ aout,
    const float* __restrict__ m0p, const float* __restrict__ l0p,
    const float* __restrict__ m1p, const float* __restrict__ l1p,
    const char* __restrict__ scratch) {
    const short* O2buf = (const short*)scratch;
    const short* O3buf = (const short*)(scratch + 4194304);
    const float* m2p = (const float*)(scratch + 8388608);
    const float* l2p = (const float*)(scratch + 8519680);
    const float* m3p = (const float*)(scratch + 8650752);
    const float* l3p = (const float*)(scratch + 8781824);
    const float* m4p = (const float*)(scratch + 8912896);
    const float* l4p = (const float*)(scratch + 9043968);

    const int s = blockIdx.x;
    int qt, bh, sA, sC = 0;
    const short* PA; const float *MA, *LA, *MB, *LB;
    const short* PC = nullptr; const float *MC = nullptr, *LC = nullptr;
    if (s < 512) {
        qt = 8 + (s >> 6); bh = s & 63; sA = s;
        PA = O0buf + (size_t)s * 8192; MA = m0p; LA = l0p; MB = m1p; LB = l1p;
        if (qt >= 12) {
            sC = (qt - 12) * 64 + bh;
            PC = O2buf + (size_t)sC * 8192; MC = m2p; LC = l2p;
        }
    } else {
        const int s3 = s - 512;
        qt = 4 + (s3 >> 6); bh = s3 & 63; sA = s3;
        PA = O3buf + (size_t)s3 * 8192; MA = m3p; LA = l3p; MB = m4p; LB = l4p;
    }
    const int b = bh >> 4;
    const int h = bh & 15;
    const int t = threadIdx.x;
    const float SCL = 0.125f * 1.44269504f;
#pragma unroll
    for (int rep = 0; rep < 2; rep++) {
        const int ql = rep * 64 + (t >> 2);       // 0..127
        const int dg = (t & 3) * 16;
        const int qi = sA * 128 + ql;
        const float m0 = MA[qi], l0 = LA[qi], m1 = MB[qi], l1 = LB[qi];
        float mm = fmaxf(m0, m1);
        float m2v = -1e30f, l2v = 0.f;
        if (PC) { m2v = MC[sC * 128 + ql]; l2v = LC[sC * 128 + ql]; mm = fmaxf(mm, m2v); }
        const float w0 = exp2f((m0 - mm) * SCL);
        const float w1 = exp2f((m1 - mm) * SCL);
        const float w2 = PC ? exp2f((m2v - mm) * SCL) : 0.f;
        const float rl = fast_rcp(l0 * w0 + l1 * w1 + l2v * w2);
        const float f0 = w0 * rl, f1 = w1 * rl, f2 = w2 * rl;
        const short* pA = PA + (size_t)ql * 64 + dg;
        const short* pC = PC ? PC + (size_t)ql * 64 + dg : nullptr;
        short* pout = aout + (size_t)(b * 2048 + qt * 128 + ql) * 1024 + h * 64 + dg;
        union { uint4 v; unsigned short u[8]; } a0, a1, a2, ov;
#pragma unroll
        for (int half = 0; half < 2; half++) {
            a0.v = ((const uint4*)pA)[half];
            a1.v = ((const uint4*)pout)[half];
            if (pC) a2.v = ((const uint4*)pC)[half];
#pragma unroll
            for (int j = 0; j < 8; j++) {
                float acc = bf2f(a0.u[j]) * f0 + bf2f(a1.u[j]) * f1;
                if (pC) acc += bf2f(a2.u[j]) * f2;
                ov.u[j] = (unsigned short)f2bf(acc);
            }
            ((uint4*)pout)[half] = ov.v;
        }
    }
}

// ---------------------------------------------------------------------------
extern "C" void kernel_launch(void* const* d_in, const int* in_sizes, int n_in,
                              void* d_out, int out_size, void* d_ws, size_t ws_size,
                              hipStream_t stream) {
    const float* x       = (const float*)d_in[0];
    const float* ln1_w   = (const float*)d_in[1];
    const float* ln1_b   = (const float*)d_in[2];
    const float* W_attn  = (const float*)d_in[3];
    const float* b_attn  = (const float*)d_in[4];
    const float* W_cproj = (const float*)d_in[5];
    const float* b_cproj = (const float*)d_in[6];
    const float* ln2_w   = (const float*)d_in[7];
    const float* ln2_b   = (const float*)d_in[8];
    const float* W_fc    = (const float*)d_in[9];
    const float* b_fc    = (const float*)d_in[10];
    const float* W_mproj = (const float*)d_in[11];
    const float* b_mproj = (const float*)d_in[12];

    char* ws = (char*)d_ws;
    short* W1t  = (short*)(ws + 0);
    short* W2t  = (short*)(ws + 6291456);
    short* W3t  = (short*)(ws + 8388608);
    short* W4t  = (short*)(ws + 16777216);
    short* h    = (short*)(ws + 25165824);
    short* aout = (short*)(ws + 41943040);
    short* big  = (short*)(ws + 58720256);   // qkv / cproj partials / fc-act
    // attention split-partial buffers inside the (dead) h region:
    short* O0buf = h;                                  // 512 slots x 16KB = 8 MB
    float* m0p = (float*)(ws + 25165824 + 8388608);           // 512*128 f32
    float* l0p = (float*)(ws + 25165824 + 8388608 + 262144);
    float* m1p = (float*)(ws + 25165824 + 8388608 + 524288);
    float* l1p = (float*)(ws + 25165824 + 8388608 + 786432);
    short* pbuf = h;                         // mproj partials [2][8192][1024]
    float* x2   = (float*)d_out;
    float* out  = (float*)d_out;
    char* scr   = (char*)d_out;              // attn scratch (dead until reduce_ln)

    // fused prologue: LN (8192 blocks) + 4x tcast (12288 blocks)
    hipLaunchKernelGGL(prep_kernel, dim3(20480), dim3(256), 0, stream,
                       x, ln1_w, ln1_b, h,
                       W_attn, W1t, W_cproj, W2t, W_fc, W3t, W_mproj, W4t);

    // qkv: 8192 x 3072 x 1024, 256^2 8-phase (384 blocks)
    hipLaunchKernelGGL((gemm256_kernel<0>), dim3(12, 32, 1), dim3(512), 131072, stream,
                       h, W1t, b_attn, (void*)big,
                       8192, 3072, 1024, 1024, 1024);

    hipLaunchKernelGGL(attn_kernel, dim3(64, 32), dim3(256), 0, stream,
                       big, aout, O0buf, m0p, l0p, m1p, l1p, scr);
    hipLaunchKernelGGL(attn_combine_kernel, dim3(768), dim3(256), 0, stream,
                       O0buf, aout, m0p, l0p, m1p, l1p, (const char*)scr);

    // cproj: K-split x2 on gemm256 (NT=8, 256 blocks), then fused reduce+ln2.
    hipLaunchKernelGGL((gemm256_kernel<3>), dim3(4, 32, 2), dim3(512), 131072, stream,
                       aout, W2t, (const float*)nullptr, (void*)big,
                       8192, 1024, 512, 1024, 1024);
    hipLaunchKernelGGL(reduce_ln_kernel, dim3(8192), dim3(256), 0, stream,
                       (const unsigned short*)big,
                       (const unsigned short*)(big + (size_t)8192 * 1024),
                       b_cproj, x, x2, ln2_w, ln2_b, h);

    // fc: 8192 x 4096 x 1024, 256^2 8-phase (512 blocks), gelu epilogue
    hipLaunchKernelGGL((gemm256_kernel<1>), dim3(16, 32, 1), dim3(512), 131072, stream,
                       h, W3t, b_fc, (void*)big,
                       8192, 4096, 1024, 1024, 1024);

    // mproj: K-split x2 (256 blocks total, NT=32), then fused reduce.
    hipLaunchKernelGGL((gemm256_kernel<3>), dim3(4, 32, 2), dim3(512), 131072, stream,
                       big, W4t, (const float*)nullptr, (void*)pbuf,
                       8192, 1024, 2048, 4096, 4096);
    hipLaunchKernelGGL(reduce_kernel, dim3(8192), dim3(256), 0, stream,
                       (const unsigned short*)pbuf,
                       (const unsigned short*)(pbuf + (size_t)8192 * 1024),
                       b_mproj, x2, out);
}

// Round 18
// 491.072 us; speedup vs baseline: 1.0194x; 1.0194x over previous
//
#include <hip/hip_runtime.h>
#include <hip/hip_bf16.h>
#include <math.h>

// ---------------------------------------------------------------------------
// GPT block fused pipeline, bf16 MFMA. B=4,S=2048,D=1024,H=16,HD=64.
// ws layout (bytes):
//   W1t  @ 0         : 3072x1024 bf16 (W_attn^T)   6291456
//   W2t  @ 6291456   : 1024x1024 bf16 (W_cproj^T)  2097152
//   W3t  @ 8388608   : 4096x1024 bf16 (W_fc^T)     8388608
//   W4t  @ 16777216  : 1024x4096 bf16 (W_mproj^T)  8388608
//   h    @ 25165824  : 8192x1024 bf16 (ln out; attn O0buf; mproj p0)
//   aout @ 41943040  : 8192x1024 bf16 (attn out; mproj partial1)
//   big  @ 58720256  : 8192x3072 bf16 qkv; then cproj partials; then fc-act
//   total 125829120 bytes.  x2 (residual after attn) lives in d_out (fp32).
// R7: GEMMs on 256^2 8-phase (T2+T3/T4+T5). R8: attn tr_read+cvt_pk.
// R14: conflict-free V staging + T14. R16: T13+T5+trees. R18: K/V dbuf,
// 1 barrier/tile. R21: prep fusion. R22: epilogue line-order (write-amp fix).
// R23: attn tail-rebalance REGRESSED (occupancy unchanged at ~19% -> not
//     tail-bound; split added 2MB fetch + 9MB write + bigger combine;
//     attn 98.4->104.8). R24: REVERT to R22 exactly (491.8us verified).
// ---------------------------------------------------------------------------

typedef __attribute__((ext_vector_type(8))) short short8;
typedef __attribute__((ext_vector_type(4))) float floatx4;
typedef __attribute__((ext_vector_type(2))) unsigned int uint2v;

#define MFMA16(a, b, c) __builtin_amdgcn_mfma_f32_16x16x32_bf16((a), (b), (c), 0, 0, 0)

__device__ __forceinline__ short f2bf(float f) {
    union { float f; unsigned u; } a; a.f = f;
    unsigned r = a.u + 0x7fffu + ((a.u >> 16) & 1u);   // round-to-nearest-even
    return (short)(r >> 16);
}

__device__ __forceinline__ float bf2f(unsigned short u) {
    union { unsigned u; float f; } a; a.u = ((unsigned)u) << 16;
    return a.f;
}

__device__ __forceinline__ float fast_rcp(float x) {
#if defined(__HIP_DEVICE_COMPILE__)
    return __builtin_amdgcn_rcpf(x);
#else
    return 1.0f / x;
#endif
}

// gelu(x) = 0.5x(1+tanh(u)) = x - x/(e^{2u}+1),  u = 0.79788456(x+0.044715x^3)
__device__ __forceinline__ float gelu_f(float x) {
    const float u = x + 0.044715f * x * x * x;
    const float t = exp2f(2.302118131f * u);   // 2*0.79788456*log2(e)*u
    return x - x * fast_rcp(t + 1.0f);
}

__device__ __forceinline__ void gload_lds16(const short* g, short* l) {
    __builtin_amdgcn_global_load_lds((const __attribute__((address_space(1))) void*)g,
                                     (__attribute__((address_space(3))) void*)l, 16, 0, 0);
}

// ---------------- fused prologue: 4x transpose-cast + LayerNorm --------------
__device__ __forceinline__ void tcast_body(const float* __restrict__ W,
                                           short* __restrict__ Wt,
                                           int K, int N, int bxi, int byi,
                                           float* __restrict__ tile) {
    const int t = threadIdx.x;
    const int tx = t & 31;
    const int ty = t >> 5;
    const int bx = bxi * 32;   // n
    const int by = byi * 32;   // k
#pragma unroll
    for (int i = 0; i < 32; i += 8)
        tile[(ty + i) * 33 + tx] = W[(size_t)(by + ty + i) * N + bx + tx];
    __syncthreads();
#pragma unroll
    for (int i = 0; i < 32; i += 8)
        Wt[(size_t)(bx + ty + i) * K + by + tx] = f2bf(tile[tx * 33 + ty + i]);
}

__global__ __launch_bounds__(256) void prep_kernel(
    const float* __restrict__ x, const float* __restrict__ ln_w,
    const float* __restrict__ ln_b, short* __restrict__ hout,
    const float* __restrict__ W_attn, short* __restrict__ W1t,
    const float* __restrict__ W_cproj, short* __restrict__ W2t,
    const float* __restrict__ W_fc, short* __restrict__ W3t,
    const float* __restrict__ W_mproj, short* __restrict__ W4t) {
    __shared__ float smem_f[32 * 33];
    int bid = blockIdx.x;
    if (bid < 8192) {
        // ---- LayerNorm row ----
        const int row = bid;
        const int t = threadIdx.x;
        const float4 v = ((const float4*)(x + (size_t)row * 1024))[t];
        float s = v.x + v.y + v.z + v.w;
        float s2 = v.x * v.x + v.y * v.y + v.z * v.z + v.w * v.w;
#pragma unroll
        for (int d = 32; d >= 1; d >>= 1) {
            s += __shfl_xor(s, d, 64);
            s2 += __shfl_xor(s2, d, 64);
        }
        float* red = smem_f;
        const int wid = t >> 6, lane = t & 63;
        if (lane == 0) { red[wid * 2] = s; red[wid * 2 + 1] = s2; }
        __syncthreads();
        s = red[0] + red[2] + red[4] + red[6];
        s2 = red[1] + red[3] + red[5] + red[7];
        const float mean = s * (1.f / 1024.f);
        const float var = s2 * (1.f / 1024.f) - mean * mean;
        const float rstd = rsqrtf(var + 1e-5f);
        const float4 wv = ((const float4*)ln_w)[t];
        const float4 bv = ((const float4*)ln_b)[t];
        union { ushort4 u; short sa[4]; } ov;
        ov.sa[0] = f2bf(wv.x * ((v.x - mean) * rstd) + bv.x);
        ov.sa[1] = f2bf(wv.y * ((v.y - mean) * rstd) + bv.y);
        ov.sa[2] = f2bf(wv.z * ((v.z - mean) * rstd) + bv.z);
        ov.sa[3] = f2bf(wv.w * ((v.w - mean) * rstd) + bv.w);
        ((ushort4*)(hout + (size_t)row * 1024))[t] = ov.u;
        return;
    }
    bid -= 8192;
    if (bid < 3072) {            // W_attn: K=1024 N=3072, gx=96
        tcast_body(W_attn, W1t, 1024, 3072, bid % 96, bid / 96, smem_f);
        return;
    }
    bid -= 3072;
    if (bid < 1024) {            // W_cproj: K=1024 N=1024, gx=32
        tcast_body(W_cproj, W2t, 1024, 1024, bid % 32, bid / 32, smem_f);
        return;
    }
    bid -= 1024;
    if (bid < 4096) {            // W_fc: K=1024 N=4096, gx=128
        tcast_body(W_fc, W3t, 1024, 4096, bid % 128, bid / 128, smem_f);
        return;
    }
    bid -= 4096;                 // W_mproj: K=4096 N=1024, gx=32
    tcast_body(W_mproj, W4t, 4096, 1024, bid % 32, bid / 32, smem_f);
}

// ------- reduce: out = bf16(p0) + bf16(p1) + bias + res (all [8192][1024]) ---
__global__ __launch_bounds__(256) void reduce_kernel(
    const unsigned short* __restrict__ p0, const unsigned short* __restrict__ p1,
    const float* __restrict__ bias, const float* __restrict__ res,
    float* __restrict__ out) {
    const int row = blockIdx.x;
    const int t = threadIdx.x;
    const size_t off = (size_t)row * 1024;
    const ushort4 a = ((const ushort4*)(p0 + off))[t];
    const ushort4 c = ((const ushort4*)(p1 + off))[t];
    const float4 r = ((const float4*)(res + off))[t];
    const float4 bv = ((const float4*)bias)[t];
    float4 o;
    o.x = bf2f(a.x) + bf2f(c.x) + bv.x + r.x;
    o.y = bf2f(a.y) + bf2f(c.y) + bv.y + r.y;
    o.z = bf2f(a.z) + bf2f(c.z) + bv.z + r.z;
    o.w = bf2f(a.w) + bf2f(c.w) + bv.w + r.w;
    ((float4*)(out + off))[t] = o;
}

// ------- fused: x2 = p0+p1+bias+res;  h = LN(x2)*w+b (saves a full pass) -----
__global__ __launch_bounds__(256) void reduce_ln_kernel(
    const unsigned short* __restrict__ p0, const unsigned short* __restrict__ p1,
    const float* __restrict__ bias, const float* __restrict__ res,
    float* __restrict__ x2out,
    const float* __restrict__ w, const float* __restrict__ b,
    short* __restrict__ hout) {
    const int row = blockIdx.x;
    const int t = threadIdx.x;
    const size_t off = (size_t)row * 1024;
    const ushort4 a = ((const ushort4*)(p0 + off))[t];
    const ushort4 c = ((const ushort4*)(p1 + off))[t];
    const float4 r = ((const float4*)(res + off))[t];
    const float4 bv = ((const float4*)bias)[t];
    float4 v;
    v.x = bf2f(a.x) + bf2f(c.x) + bv.x + r.x;
    v.y = bf2f(a.y) + bf2f(c.y) + bv.y + r.y;
    v.z = bf2f(a.z) + bf2f(c.z) + bv.z + r.z;
    v.w = bf2f(a.w) + bf2f(c.w) + bv.w + r.w;
    ((float4*)(x2out + off))[t] = v;
    float s = v.x + v.y + v.z + v.w;
    float s2 = v.x * v.x + v.y * v.y + v.z * v.z + v.w * v.w;
#pragma unroll
    for (int d = 32; d >= 1; d >>= 1) {
        s += __shfl_xor(s, d, 64);
        s2 += __shfl_xor(s2, d, 64);
    }
    __shared__ float red[8];
    const int wid = t >> 6, lane = t & 63;
    if (lane == 0) { red[wid * 2] = s; red[wid * 2 + 1] = s2; }
    __syncthreads();
    s = red[0] + red[2] + red[4] + red[6];
    s2 = red[1] + red[3] + red[5] + red[7];
    const float mean = s * (1.f / 1024.f);
    const float var = s2 * (1.f / 1024.f) - mean * mean;
    const float rstd = rsqrtf(var + 1e-5f);
    const float4 wv = ((const float4*)w)[t];
    const float4 lb = ((const float4*)b)[t];
    union { ushort4 u; short sa[4]; } ov;
    ov.sa[0] = f2bf(wv.x * ((v.x - mean) * rstd) + lb.x);
    ov.sa[1] = f2bf(wv.y * ((v.y - mean) * rstd) + lb.y);
    ov.sa[2] = f2bf(wv.z * ((v.z - mean) * rstd) + lb.z);
    ov.sa[3] = f2bf(wv.w * ((v.w - mean) * rstd) + lb.w);
    ((ushort4*)(hout + (size_t)row * 1024))[t] = ov.u;
}

// ---------------- GEMM 256^2 8-phase (qkv / cproj / fc / mproj) --------------
#define GBAR()  asm volatile("s_barrier" ::: "memory")
#define LGKM0() asm volatile("s_waitcnt lgkmcnt(0)" ::: "memory")
#define STAGE_A(b_, kt_, p_)                                                   \
    do {                                                                       \
        gload_lds16(gA + (size_t)((p_) * 128) * lda + (kt_) * 64,              \
                    lA + (b_) * 16384 + (p_) * 8192);                          \
        gload_lds16(gA + (size_t)((p_) * 128 + 64) * lda + (kt_) * 64,         \
                    lA + (b_) * 16384 + (p_) * 8192 + 4096);                   \
    } while (0)
#define STAGE_B(b_, kt_, p_)                                                   \
    do {                                                                       \
        gload_lds16(gB + (size_t)((p_) * 128) * ldb + (kt_) * 64,              \
                    lB + (b_) * 16384 + (p_) * 8192);                          \
        gload_lds16(gB + (size_t)((p_) * 128 + 64) * ldb + (kt_) * 64,         \
                    lB + (b_) * 16384 + (p_) * 8192 + 4096);                   \
    } while (0)

template <int EPI>
__global__ __launch_bounds__(512, 2) void gemm256_kernel(
    const short* __restrict__ A, const short* __restrict__ Bt,
    const float* __restrict__ bias,
    void* __restrict__ Cout, int M, int N, int Klen, int lda, int ldb) {
    extern __shared__ __align__(16) short lds[];
    short* As = lds;             // [2][256][64]
    short* Bs = lds + 32768;     // [2][256][64]

    const int tid = threadIdx.x;
    const int wid = tid >> 6;
    const int lane = tid & 63;
    const int quad = lane >> 4;
    const int l16 = lane & 15;
    const int l7 = l16 & 7;
    const int warp_m = wid >> 2;       // 0..1
    const int warp_n = wid & 3;        // 0..3

    const unsigned gx = gridDim.x;
    const unsigned bid2 = blockIdx.x + gx * blockIdx.y;   // gridDim.y == 32
    const unsigned xcd = bid2 & 7;
    const unsigned loc = bid2 >> 3;
    const unsigned nb = loc % gx;
    const unsigned mhi = loc / gx;     // 0..3
    const int m0 = (int)(mhi * 8 + xcd) * 256;
    const int n0 = (int)nb * 256;
    const int kbase = blockIdx.z * Klen;
    const int NT = Klen >> 6;

    // staging: thread covers dest byte o = i*8192 + tid*16 of a 256x128B tile.
    const int rsub = tid >> 3;
    const int scol = ((tid & 7) ^ (rsub & 7)) << 3;      // shorts
    const short* gA = A + (size_t)(m0 + rsub) * lda + kbase + scol;
    const short* gB = Bt + (size_t)(n0 + rsub) * ldb + kbase + scol;
    short* lA = As + wid * 512;        // + b*16384 + i*4096  (wave-uniform)
    short* lB = Bs + wid * 512;

    // ds_read swizzle: logical col bytes = ks*64 + quad*16; bits[6:4] ^= l7.
    const int sk0 = ((0 | quad) ^ l7) << 3;              // shorts, ks=0
    const int sk1 = ((4 | quad) ^ l7) << 3;              // shorts, ks=1

    floatx4 acc[8][4] = {};
    short8 afrag[4][2], bA[2][2], bB[2][2];

    // ---- prologue: tile0 fully + H1(1); wait leaving H1(1) in flight -------
    STAGE_A(0, 0, 0); STAGE_A(0, 0, 1);
    STAGE_B(0, 0, 0); STAGE_B(0, 0, 1);
    if (NT > 1) {
        STAGE_A(1, 1, 0);
        asm volatile("s_waitcnt vmcnt(2)" ::: "memory");
    } else {
        asm volatile("s_waitcnt vmcnt(0)" ::: "memory");
    }
    GBAR();

    for (int t = 0; t < NT; ++t) {
        const int b = t & 1;
        const int bn = b ^ 1;
        const short* Ab = As + b * 16384 + (warp_m * 128 + l16) * 64;
        const short* Bb = Bs + b * 16384 + (warp_n * 64 + l16) * 64;
        // ---------------- P1: read A(mi0-3), B(ni0-1); stage H2(t+1) --------
#pragma unroll
        for (int mi = 0; mi < 4; mi++) {
            afrag[mi][0] = *(const short8*)(Ab + mi * 1024 + sk0);
            afrag[mi][1] = *(const short8*)(Ab + mi * 1024 + sk1);
        }
#pragma unroll
        for (int ni = 0; ni < 2; ni++) {
            bA[ni][0] = *(const short8*)(Bb + ni * 1024 + sk0);
            bA[ni][1] = *(const short8*)(Bb + ni * 1024 + sk1);
        }
        if (t + 1 < NT) STAGE_A(bn, t + 1, 1);
        GBAR(); LGKM0();
        __builtin_amdgcn_s_setprio(1);
#pragma unroll
        for (int mi = 0; mi < 4; mi++)
#pragma unroll
            for (int ni = 0; ni < 2; ni++) {
                acc[mi][ni] = MFMA16(afrag[mi][0], bA[ni][0], acc[mi][ni]);
                acc[mi][ni] = MFMA16(afrag[mi][1], bA[ni][1], acc[mi][ni]);
            }
        __builtin_amdgcn_s_setprio(0);
        GBAR();
        // ---------------- P2: read B(ni2-3); stage H3(t+1) ------------------
#pragma unroll
        for (int ni = 0; ni < 2; ni++) {
            bB[ni][0] = *(const short8*)(Bb + (2 + ni) * 1024 + sk0);
            bB[ni][1] = *(const short8*)(Bb + (2 + ni) * 1024 + sk1);
        }
        if (t + 1 < NT) STAGE_B(bn, t + 1, 0);
        GBAR(); LGKM0();
        __builtin_amdgcn_s_setprio(1);
#pragma unroll
        for (int mi = 0; mi < 4; mi++)
#pragma unroll
            for (int ni = 0; ni < 2; ni++) {
                acc[mi][2 + ni] = MFMA16(afrag[mi][0], bB[ni][0], acc[mi][2 + ni]);
                acc[mi][2 + ni] = MFMA16(afrag[mi][1], bB[ni][1], acc[mi][2 + ni]);
            }
        __builtin_amdgcn_s_setprio(0);
        GBAR();
        // ---------------- P3: read A(mi4-7); stage H4(t+1) ------------------
#pragma unroll
        for (int mi = 0; mi < 4; mi++) {
            afrag[mi][0] = *(const short8*)(Ab + (4 + mi) * 1024 + sk0);
            afrag[mi][1] = *(const short8*)(Ab + (4 + mi) * 1024 + sk1);
        }
        if (t + 1 < NT) STAGE_B(bn, t + 1, 1);
        GBAR(); LGKM0();
        __builtin_amdgcn_s_setprio(1);
#pragma unroll
        for (int mi = 0; mi < 4; mi++)
#pragma unroll
            for (int ni = 0; ni < 2; ni++) {
                acc[4 + mi][2 + ni] = MFMA16(afrag[mi][0], bB[ni][0], acc[4 + mi][2 + ni]);
                acc[4 + mi][2 + ni] = MFMA16(afrag[mi][1], bB[ni][1], acc[4 + mi][2 + ni]);
            }
        __builtin_amdgcn_s_setprio(0);
        GBAR();
        // ---------------- P4: stage H1(t+2); counted vmcnt ------------------
        if (t + 2 < NT) STAGE_A(b, t + 2, 0);
        GBAR();
        __builtin_amdgcn_s_setprio(1);
#pragma unroll
        for (int mi = 0; mi < 4; mi++)
#pragma unroll
            for (int ni = 0; ni < 2; ni++) {
                acc[4 + mi][ni] = MFMA16(afrag[mi][0], bA[ni][0], acc[4 + mi][ni]);
                acc[4 + mi][ni] = MFMA16(afrag[mi][1], bA[ni][1], acc[4 + mi][ni]);
            }
        __builtin_amdgcn_s_setprio(0);
        if (t + 2 < NT) asm volatile("s_waitcnt vmcnt(2)" ::: "memory");
        else            asm volatile("s_waitcnt vmcnt(0)" ::: "memory");
        GBAR();
    }

    // ---- epilogue (R22: line-completing store order, ni innermost) ---------
    float bv4[4] = {0.f, 0.f, 0.f, 0.f};
    if constexpr (EPI != 3) {
#pragma unroll
        for (int ni = 0; ni < 4; ni++)
            bv4[ni] = bias[n0 + warp_n * 64 + ni * 16 + l16];
    }
#pragma unroll
    for (int mi = 0; mi < 8; mi++) {
#pragma unroll
        for (int r = 0; r < 4; r++) {
            const int row = m0 + warp_m * 128 + mi * 16 + quad * 4 + r;
            const size_t rowoff = (size_t)row * N + n0 + warp_n * 64 + l16;
#pragma unroll
            for (int ni = 0; ni < 4; ni++) {
                const size_t idx = rowoff + ni * 16;
                float v = acc[mi][ni][r] + bv4[ni];
                if constexpr (EPI == 0) {
                    ((short*)Cout)[idx] = f2bf(v);
                } else if constexpr (EPI == 1) {
                    ((short*)Cout)[idx] = f2bf(gelu_f(v));
                } else {
                    ((short*)Cout)[(size_t)blockIdx.z * M * N + idx] = f2bf(v);
                }
            }
        }
    }
}
#undef STAGE_A
#undef STAGE_B
#undef GBAR
#undef LGKM0

// ---------------- causal flash attention (S^T formulation, K-split) ----------
// blockIdx.y in [0,24):
//   y in [0,8)   : qt = 8+y,  keys [0,1024)          -> partial0 (O0buf + m0/l0)
//   y in [8,16)  : qt = 15-y, keys [0,(qt+1)*128) direct
//   y in [16,24) : qt = 8+(23-y), keys [1024, (qt+1)*128) -> partial1
// Longest blocks dispatch earliest. Partials are UNNORMALIZED (O' = sum p*v).
// V staged subtiled Vt[dg=4][kb=16][4][16]; PV A-frags via ds_read_b64_tr_b16.
// R14 staging (T14 + conflict-free): K thread (r=tid>>2,cg) -> regs -> Ks;
// V wave-per-dgi lane-contiguous writes; next-tile loads issued pre-barrier.
// R16: T13 defer-max, T5 setprio, tree reductions.
// R18: double-buffered K/V (buf = kt&1) -> single __syncthreads per k-tile;
// one extra sync before Ow epilogue (smem reuse).
__global__ __launch_bounds__(256) void attn_kernel(
    const short* __restrict__ qkv, short* __restrict__ aout,
    short* __restrict__ O0buf, float* __restrict__ m0p, float* __restrict__ l0p,
    float* __restrict__ m1p, float* __restrict__ l1p) {
    __shared__ __align__(16) short smem[18432];  // 2 x (Ks[64][72] | Vt[4096])
    short* Ks = smem;                            // + (kt&1)*9216
    short* Vt = smem + 64 * 72;

    const int tid = threadIdx.x;
    const int wid = tid >> 6;
    const int lane = tid & 63;
    const int quad = lane >> 4;
    const int l16 = lane & 15;

    const int y = blockIdx.y;
    int qt, ktlo, kthi, mode;
    if (y < 8)       { qt = 8 + y;        ktlo = 0;  kthi = 16;             mode = 1; }
    else if (y < 16) { qt = 15 - y;       ktlo = 0;  kthi = (qt + 1) * 2;   mode = 0; }
    else             { qt = 8 + (23 - y); ktlo = 16; kthi = (qt + 1) * 2;   mode = 2; }
    const int q0 = qt * 128;
    const int bh = blockIdx.x;
    const int b = bh >> 4;
    const int h = bh & 15;

    const short* base = qkv + (size_t)b * 2048 * 3072 + h * 64;
    const int qrow_base = q0 + wid * 32;

    short8 qf[2][2];
#pragma unroll
    for (int qt_i = 0; qt_i < 2; qt_i++)
#pragma unroll
        for (int ks = 0; ks < 2; ks++)
            qf[qt_i][ks] = *(const short8*)(base +
                (size_t)(qrow_base + qt_i * 16 + l16) * 3072 + ks * 32 + quad * 8);

    // ---- staging addresses (R14) ----
    const int kr_ = tid >> 2;                 // K row 0..63
    const int kcg = (tid & 3) * 16;           // K col group (shorts)
    const short* ksrc = base + 1024 + kcg;    // + (kt0+kr_)*3072
    short* kdst = &Ks[kr_ * 72 + kcg];
    const int vrA = ((lane >> 3) << 2) | ((lane >> 1) & 3);   // V row (lane-local)
    const short* vsrc = base + 2048 + wid * 16 + (lane & 1) * 8;  // + (kt0+row)*3072
    short* vdst = Vt + wid * 1024 + lane * 8;  // bytes w*2048 + i*16; +512 shorts

    // lane-local byte address into Vt for ds_read_b64_tr_b16
    const unsigned vaddr0 =
        (unsigned)(size_t)(__attribute__((address_space(3))) void*)Vt +
        (unsigned)(quad * 128 + l16 * 8);

    union VF { short8 s; uint2v h2[2]; };
    union PK { short8 s; unsigned u[4]; };

    floatx4 o[4][2] = {};           // O^T: [dt][qt_i]
    float mrow[2] = {-1e30f, -1e30f};
    float lrow[2] = {0.f, 0.f};
    const float SCL = 0.125f * 1.44269504f;  // raw-score -> log2 units

    uint4 krg0, krg1, vrg0, vrg1;
#define LOADREG(kt0_)                                                          \
    do {                                                                       \
        const short* kp = ksrc + (size_t)((kt0_) + kr_) * 3072;                \
        krg0 = ((const uint4*)kp)[0];                                          \
        krg1 = ((const uint4*)kp)[1];                                          \
        vrg0 = *(const uint4*)(vsrc + (size_t)((kt0_) + vrA) * 3072);          \
        vrg1 = *(const uint4*)(vsrc + (size_t)((kt0_) + vrA + 32) * 3072);     \
    } while (0)

    LOADREG(ktlo * 64);
    for (int kt = ktlo; kt < kthi; kt++) {
        const int kt0 = kt * 64;
        const int bo = (kt & 1) * 9216;            // LDS buffer offset (shorts)
        // write staged regs to LDS buf[kt&1], then issue next tile's loads
        *(uint4*)(kdst + bo) = krg0;
        *(uint4*)(kdst + bo + 8) = krg1;
        *(uint4*)(vdst + bo) = vrg0;
        *(uint4*)(vdst + bo + 512) = vrg1;
        if (kt + 1 < kthi) LOADREG((kt + 1) * 64);
        __syncthreads();   // writes of buf[kt&1] visible; also orders the
                           // re-write of buf[(kt+1)&1] after all reads of it
                           // (compute kt-1 precedes each wave's entry here)
        if (kt0 <= qrow_base + 31) {
            floatx4 st[4][2] = {};
            __builtin_amdgcn_s_setprio(1);
#pragma unroll
            for (int kti = 0; kti < 4; kti++) {
                const short8 kf0 = *(const short8*)&Ks[bo + (kti * 16 + l16) * 72 + quad * 8];
                const short8 kf1 = *(const short8*)&Ks[bo + (kti * 16 + l16) * 72 + 32 + quad * 8];
#pragma unroll
                for (int qt_i = 0; qt_i < 2; qt_i++) {
                    st[kti][qt_i] = MFMA16(kf0, qf[qt_i][0], st[kti][qt_i]);
                    st[kti][qt_i] = MFMA16(kf1, qf[qt_i][1], st[kti][qt_i]);
                }
            }
            __builtin_amdgcn_s_setprio(0);
            // issue all 16 V transpose-reads now; latency hides under softmax.
            const unsigned va = vaddr0 + (unsigned)(bo * 2);
            VF vf[2][4];   // [c][dt]; offset = dt*2048 + c*1024 + h*512 bytes
#define TRRD(dst, offs) \
    asm volatile("ds_read_b64_tr_b16 %0, %1 offset:" offs : "=v"(dst) : "v"(va))
            TRRD(vf[0][0].h2[0], "0");    TRRD(vf[0][0].h2[1], "512");
            TRRD(vf[0][1].h2[0], "2048"); TRRD(vf[0][1].h2[1], "2560");
            TRRD(vf[0][2].h2[0], "4096"); TRRD(vf[0][2].h2[1], "4608");
            TRRD(vf[0][3].h2[0], "6144"); TRRD(vf[0][3].h2[1], "6656");
            TRRD(vf[1][0].h2[0], "1024"); TRRD(vf[1][0].h2[1], "1536");
            TRRD(vf[1][1].h2[0], "3072"); TRRD(vf[1][1].h2[1], "3584");
            TRRD(vf[1][2].h2[0], "5120"); TRRD(vf[1][2].h2[1], "5632");
            TRRD(vf[1][3].h2[0], "7168"); TRRD(vf[1][3].h2[1], "7680");
#undef TRRD
            const bool needmask = (kt0 + 63) > qrow_base;
            PK pk[2][2];
#pragma unroll
            for (int qt_i = 0; qt_i < 2; qt_i++) {
                const int q = qrow_base + qt_i * 16 + l16;
                if (needmask) {
#pragma unroll
                    for (int kti = 0; kti < 4; kti++)
#pragma unroll
                        for (int r = 0; r < 4; r++)
                            if ((kt0 + kti * 16 + quad * 4 + r) > q) st[kti][qt_i][r] = -1e30f;
                }
                // tree max (depth 4; serial chain would be 15 dependent fmax)
                float mk[4];
#pragma unroll
                for (int kti = 0; kti < 4; kti++)
                    mk[kti] = fmaxf(fmaxf(st[kti][qt_i][0], st[kti][qt_i][1]),
                                    fmaxf(st[kti][qt_i][2], st[kti][qt_i][3]));
                float mx = fmaxf(fmaxf(mk[0], mk[1]), fmaxf(mk[2], mk[3]));
                mx = fmaxf(mx, __shfl_xor(mx, 16, 64));
                mx = fmaxf(mx, __shfl_xor(mx, 32, 64));
                // T13 defer-max: only rescale when some row grew by > 8 (raw).
                if (!__all((mx - mrow[qt_i]) <= 8.0f)) {
                    const float mnew = fmaxf(mrow[qt_i], mx);
                    const float alpha = exp2f((mrow[qt_i] - mnew) * SCL);
                    mrow[qt_i] = mnew;
                    lrow[qt_i] *= alpha;
#pragma unroll
                    for (int dt = 0; dt < 4; dt++) o[dt][qt_i] *= alpha;
                }
                const float nm = -mrow[qt_i] * SCL;
#pragma unroll
                for (int kti = 0; kti < 4; kti++)
#pragma unroll
                    for (int r = 0; r < 4; r++)
                        st[kti][qt_i][r] = exp2f(fmaf(st[kti][qt_i][r], SCL, nm));
                // tree sum
                float sk_[4];
#pragma unroll
                for (int kti = 0; kti < 4; kti++)
                    sk_[kti] = (st[kti][qt_i][0] + st[kti][qt_i][1]) +
                               (st[kti][qt_i][2] + st[kti][qt_i][3]);
                float ps = (sk_[0] + sk_[1]) + (sk_[2] + sk_[3]);
                ps += __shfl_xor(ps, 16, 64);
                ps += __shfl_xor(ps, 32, 64);
                lrow[qt_i] += ps;
                // P -> bf16 via packed converts
#define CVTPK(dst, lo, hi) \
    asm("v_cvt_pk_bf16_f32 %0, %1, %2" : "=v"(dst) : "v"(lo), "v"(hi))
                CVTPK(pk[0][qt_i].u[0], st[0][qt_i][0], st[0][qt_i][1]);
                CVTPK(pk[0][qt_i].u[1], st[0][qt_i][2], st[0][qt_i][3]);
                CVTPK(pk[0][qt_i].u[2], st[1][qt_i][0], st[1][qt_i][1]);
                CVTPK(pk[0][qt_i].u[3], st[1][qt_i][2], st[1][qt_i][3]);
                CVTPK(pk[1][qt_i].u[0], st[2][qt_i][0], st[2][qt_i][1]);
                CVTPK(pk[1][qt_i].u[1], st[2][qt_i][2], st[2][qt_i][3]);
                CVTPK(pk[1][qt_i].u[2], st[3][qt_i][0], st[3][qt_i][1]);
                CVTPK(pk[1][qt_i].u[3], st[3][qt_i][2], st[3][qt_i][3]);
#undef CVTPK
            }
            asm volatile("s_waitcnt lgkmcnt(0)" ::: "memory");
            __builtin_amdgcn_sched_barrier(0);
            __builtin_amdgcn_s_setprio(1);
#pragma unroll
            for (int c = 0; c < 2; c++)
#pragma unroll
                for (int dt = 0; dt < 4; dt++) {
                    o[dt][0] = MFMA16(vf[c][dt].s, pk[c][0].s, o[dt][0]);
                    o[dt][1] = MFMA16(vf[c][dt].s, pk[c][1].s, o[dt][1]);
                }
            __builtin_amdgcn_s_setprio(0);
        }
        // no trailing barrier: next iteration writes the OTHER buffer.
    }
#undef LOADREG
    __syncthreads();   // all waves done with K/V buffers before Ow reuse
    // epilogue: (maybe normalize), per-wave transpose O^T->O via LDS, store
    const int slot = (qt - 8) * 64 + bh;   // valid for modes 1/2
    short* Ow = smem + wid * (32 * 72);
    const float rl0 = (mode == 0) ? fast_rcp(lrow[0]) : 1.0f;
    const float rl1 = (mode == 0) ? fast_rcp(lrow[1]) : 1.0f;
#pragma unroll
    for (int dt = 0; dt < 4; dt++)
#pragma unroll
        for (int r = 0; r < 4; r++) {
            Ow[(l16) * 72 + dt * 16 + quad * 4 + r] = f2bf(o[dt][0][r] * rl0);
            Ow[(16 + l16) * 72 + dt * 16 + quad * 4 + r] = f2bf(o[dt][1][r] * rl1);
        }
    if (mode != 0 && quad == 0) {   // per-q m/l (q = qrow_base + qt_i*16 + l16)
        const int qi0 = slot * 128 + (qrow_base - q0) + l16;
        if (mode == 1) {
            m0p[qi0] = mrow[0]; l0p[qi0] = lrow[0];
            m0p[qi0 + 16] = mrow[1]; l0p[qi0 + 16] = lrow[1];
        } else {
            m1p[qi0] = mrow[0]; l1p[qi0] = lrow[0];
            m1p[qi0 + 16] = mrow[1]; l1p[qi0 + 16] = lrow[1];
        }
    }
    __asm__ volatile("s_waitcnt lgkmcnt(0)" ::: "memory");
    {
        const int ql = lane >> 1;
        const int h2 = lane & 1;
        short* orow;
        if (mode == 1)
            orow = O0buf + (size_t)slot * 8192 + (size_t)(wid * 32 + ql) * 64 + h2 * 32;
        else
            orow = aout + (size_t)(b * 2048 + q0 + wid * 32 + ql) * 1024 + h * 64 + h2 * 32;
#pragma unroll
        for (int s = 0; s < 4; s++)
            *(uint4*)(orow + s * 8) = *(const uint4*)&Ow[ql * 72 + h2 * 32 + s * 8];
    }
}

// ------- attention combine: aout = (O0*w0 + O1*w1) / (l0*w0 + l1*w1) ---------
__global__ __launch_bounds__(256) void attn_combine_kernel(
    const short* __restrict__ O0buf, short* __restrict__ aout,
    const float* __restrict__ m0p, const float* __restrict__ l0p,
    const float* __restrict__ m1p, const float* __restrict__ l1p) {
    const int slot = blockIdx.x;           // (qt-8)*64 + bh
    const int qt = 8 + (slot >> 6);
    const int bh = slot & 63;
    const int b = bh >> 4;
    const int h = bh & 15;
    const int t = threadIdx.x;
    const float SCL = 0.125f * 1.44269504f;
#pragma unroll
    for (int rep = 0; rep < 2; rep++) {
        const int ql = rep * 64 + (t >> 2);       // 0..127
        const int dg = (t & 3) * 16;
        const int qi = slot * 128 + ql;
        const float m0 = m0p[qi], l0 = l0p[qi], m1 = m1p[qi], l1 = l1p[qi];
        const float mm = fmaxf(m0, m1);
        const float w0 = exp2f((m0 - mm) * SCL);
        const float w1 = exp2f((m1 - mm) * SCL);
        const float rl = fast_rcp(fmaf(l0, w0, l1 * w1));
        const float f0 = w0 * rl, f1 = w1 * rl;
        const short* p0 = O0buf + (size_t)slot * 8192 + (size_t)ql * 64 + dg;
        short* pout = aout + (size_t)(b * 2048 + qt * 128 + ql) * 1024 + h * 64 + dg;
        union { uint4 v; unsigned short u[8]; } a0, a1, ov;
#pragma unroll
        for (int half = 0; half < 2; half++) {
            a0.v = ((const uint4*)p0)[half];
            a1.v = ((const uint4*)pout)[half];
#pragma unroll
            for (int j = 0; j < 8; j++)
                ov.u[j] = (unsigned short)f2bf(bf2f(a0.u[j]) * f0 + bf2f(a1.u[j]) * f1);
            ((uint4*)pout)[half] = ov.v;
        }
    }
}

// ---------------------------------------------------------------------------
extern "C" void kernel_launch(void* const* d_in, const int* in_sizes, int n_in,
                              void* d_out, int out_size, void* d_ws, size_t ws_size,
                              hipStream_t stream) {
    const float* x       = (const float*)d_in[0];
    const float* ln1_w   = (const float*)d_in[1];
    const float* ln1_b   = (const float*)d_in[2];
    const float* W_attn  = (const float*)d_in[3];
    const float* b_attn  = (const float*)d_in[4];
    const float* W_cproj = (const float*)d_in[5];
    const float* b_cproj = (const float*)d_in[6];
    const float* ln2_w   = (const float*)d_in[7];
    const float* ln2_b   = (const float*)d_in[8];
    const float* W_fc    = (const float*)d_in[9];
    const float* b_fc    = (const float*)d_in[10];
    const float* W_mproj = (const float*)d_in[11];
    const float* b_mproj = (const float*)d_in[12];

    char* ws = (char*)d_ws;
    short* W1t  = (short*)(ws + 0);
    short* W2t  = (short*)(ws + 6291456);
    short* W3t  = (short*)(ws + 8388608);
    short* W4t  = (short*)(ws + 16777216);
    short* h    = (short*)(ws + 25165824);
    short* aout = (short*)(ws + 41943040);
    short* big  = (short*)(ws + 58720256);   // qkv / cproj partials / fc-act
    // attention split-partial buffers inside the (dead) h region:
    short* O0buf = h;                                  // 512 * 8192 bf16 = 8 MB
    float* m0p = (float*)(ws + 25165824 + 8388608);           // 512*128 f32
    float* l0p = (float*)(ws + 25165824 + 8388608 + 262144);
    float* m1p = (float*)(ws + 25165824 + 8388608 + 524288);
    float* l1p = (float*)(ws + 25165824 + 8388608 + 786432);
    short* pbuf = h;                         // mproj partials [2][8192][1024]
    float* x2   = (float*)d_out;
    float* out  = (float*)d_out;

    // fused prologue: LN (8192 blocks) + 4x tcast (12288 blocks)
    hipLaunchKernelGGL(prep_kernel, dim3(20480), dim3(256), 0, stream,
                       x, ln1_w, ln1_b, h,
                       W_attn, W1t, W_cproj, W2t, W_fc, W3t, W_mproj, W4t);

    // qkv: 8192 x 3072 x 1024, 256^2 8-phase (384 blocks)
    hipLaunchKernelGGL((gemm256_kernel<0>), dim3(12, 32, 1), dim3(512), 131072, stream,
                       h, W1t, b_attn, (void*)big,
                       8192, 3072, 1024, 1024, 1024);

    hipLaunchKernelGGL(attn_kernel, dim3(64, 24), dim3(256), 0, stream,
                       big, aout, O0buf, m0p, l0p, m1p, l1p);
    hipLaunchKernelGGL(attn_combine_kernel, dim3(512), dim3(256), 0, stream,
                       O0buf, aout, m0p, l0p, m1p, l1p);

    // cproj: K-split x2 on gemm256 (NT=8, 256 blocks), then fused reduce+ln2.
    hipLaunchKernelGGL((gemm256_kernel<3>), dim3(4, 32, 2), dim3(512), 131072, stream,
                       aout, W2t, (const float*)nullptr, (void*)big,
                       8192, 1024, 512, 1024, 1024);
    hipLaunchKernelGGL(reduce_ln_kernel, dim3(8192), dim3(256), 0, stream,
                       (const unsigned short*)big,
                       (const unsigned short*)(big + (size_t)8192 * 1024),
                       b_cproj, x, x2, ln2_w, ln2_b, h);

    // fc: 8192 x 4096 x 1024, 256^2 8-phase (512 blocks), gelu epilogue
    hipLaunchKernelGGL((gemm256_kernel<1>), dim3(16, 32, 1), dim3(512), 131072, stream,
                       h, W3t, b_fc, (void*)big,
                       8192, 4096, 1024, 1024, 1024);

    // mproj: K-split x2 (256 blocks total, NT=32), then fused reduce.
    hipLaunchKernelGGL((gemm256_kernel<3>), dim3(4, 32, 2), dim3(512), 131072, stream,
                       big, W4t, (const float*)nullptr, (void*)pbuf,
                       8192, 1024, 2048, 4096, 4096);
    hipLaunchKernelGGL(reduce_kernel, dim3(8192), dim3(256), 0, stream,
                       (const unsigned short*)pbuf,
                       (const unsigned short*)(pbuf + (size_t)8192 * 1024),
                       b_mproj, x2, out);
}